// Round 7
// baseline (115.212 us; speedup 1.0000x reference)
//
#include <hip/hip_runtime.h>

// PointPillarsScatter: canvas[b, :, y, x] = feat[p, :], last-writer-wins.
// Phase 1: memset winner; Phase 2: winner[b,y,x] = max(p)+1 via atomicMax;
// Phase 3: LDS-transpose gather. Block owns 64 consecutive quads (256 cells):
//   load:  16 lanes per pillar row -> 256B coalesced feat reads, written
//          channel-major into tr[64][257] via 4 scalar ds_writes
//          (bank idx = 4*ln+grp+16r mod 32 -> 2 lanes/bank = conflict-free).
//   store: wave per channel: one conflict-free ds_read_b128 + ONE 1KB
//          contiguous nontemporal store per wave-instr (fill-kernel footprint).
// vs R6: store run length 512B->1KB, store-phase LDS conflicts 4-way->0.

constexpr int HH  = 496;
constexpr int WW  = 432;
constexpr int CC  = 64;
constexpr int HWp = HH * WW;    // 214272
constexpr int W4  = WW / 4;     // 108
constexpr int CELLS2 = 256;     // cells per block (64 quads)
constexpr int PAD2   = 257;     // LDS cell stride (odd -> bank-friendly)

typedef float v4f __attribute__((ext_vector_type(4)));

// Zero-initialized device global: the "feature row" of empty cells (fallback).
__device__ float g_zero_row[CC];

__global__ void k_winner(const int* __restrict__ coords, int* __restrict__ winner,
                         int wstride, int P) {
    int p = blockIdx.x * blockDim.x + threadIdx.x;
    if (p >= P) return;
    int4 c4 = reinterpret_cast<const int4*>(coords)[p];  // (b, z, y, x)
    atomicMax(&winner[c4.x * wstride + c4.z * WW + c4.w], p + 1);
}

__global__ __launch_bounds__(256) void k_gather_lds2(
        const float* __restrict__ feat, const int* __restrict__ winner,
        float* __restrict__ out, int blocksPerBatch) {
    __shared__ float tr[CC * PAD2];   // 64 x 257 floats = 65,792 B -> 2 blocks/CU

    const int bb       = blockIdx.x / blocksPerBatch;
    const int cellbase = (blockIdx.x % blocksPerBatch) * CELLS2;
    const int t   = threadIdx.x;
    const int grp = t >> 4;   // 0..15 (row group in load phase)
    const int ln  = t & 15;   // 0..15 (channel-quad lane)

    const int* wbase = winner + bb * HWp + cellbase;

    // --- load phase: 16 rounds x 16 rows; channel-major LDS (transposed) ---
    #pragma unroll
    for (int r = 0; r < 16; ++r) {
        int row = r * 16 + grp;
        int w = wbase[row];                       // broadcast within 16-lane group
        v4f v = {0.0f, 0.0f, 0.0f, 0.0f};
        if (w > 0)
            v = *reinterpret_cast<const v4f*>(feat + (size_t)(w - 1) * CC + ln * 4);
        tr[(ln * 4 + 0) * PAD2 + row] = v.x;
        tr[(ln * 4 + 1) * PAD2 + row] = v.y;
        tr[(ln * 4 + 2) * PAD2 + row] = v.z;
        tr[(ln * 4 + 3) * PAD2 + row] = v.w;
    }
    __syncthreads();

    // --- store phase: 16 rounds; each wave = one channel, 1KB contiguous ---
    const int qv  = t & 63;   // lane within wave
    const int wid = t >> 6;   // wave id 0..3
    float* obase = out + (size_t)bb * CC * HWp + cellbase;
    #pragma unroll
    for (int r = 0; r < 16; ++r) {
        int c = r * 4 + wid;
        v4f s = *reinterpret_cast<const v4f*>(&tr[c * PAD2 + qv * 4]);
        __builtin_nontemporal_store(
            s, reinterpret_cast<v4f*>(obase + (size_t)c * HWp + qv * 4));
    }
}

// ---- fallback gather (ws too small): winner lives in out's c=0 plane.
// Thread-per-cell, reads its own winner quad exactly once before overwriting.
__global__ __launch_bounds__(256) void k_gather_cells(
        const float* __restrict__ feat, const int* __restrict__ winner,
        int wstride, float* __restrict__ out, int total) {
    int t = blockIdx.x * blockDim.x + threadIdx.x;
    if (t >= total) return;
    int x4 = t % W4;  int r = t / W4;
    int y  = r % HH;  int bb = r / HH;
    const int4 win = *reinterpret_cast<const int4*>(
        &winner[bb * wstride + y * WW + x4 * 4]);
    const float* f0 = (win.x > 0) ? feat + (size_t)(win.x - 1) * CC : g_zero_row;
    const float* f1 = (win.y > 0) ? feat + (size_t)(win.y - 1) * CC : g_zero_row;
    const float* f2 = (win.z > 0) ? feat + (size_t)(win.z - 1) * CC : g_zero_row;
    const float* f3 = (win.w > 0) ? feat + (size_t)(win.w - 1) * CC : g_zero_row;
    float* ob = out + ((size_t)bb * CC * HH + y) * WW + x4 * 4;
    #pragma unroll 4
    for (int cq = 0; cq < CC / 4; ++cq) {
        v4f a = *reinterpret_cast<const v4f*>(f0 + cq * 4);
        v4f b = *reinterpret_cast<const v4f*>(f1 + cq * 4);
        v4f c = *reinterpret_cast<const v4f*>(f2 + cq * 4);
        v4f d = *reinterpret_cast<const v4f*>(f3 + cq * 4);
        float* o = ob + (size_t)cq * 4 * HWp;
        v4f s0 = {a.x, b.x, c.x, d.x};
        v4f s1 = {a.y, b.y, c.y, d.y};
        v4f s2 = {a.z, b.z, c.z, d.z};
        v4f s3 = {a.w, b.w, c.w, d.w};
        __builtin_nontemporal_store(s0, reinterpret_cast<v4f*>(o));
        __builtin_nontemporal_store(s1, reinterpret_cast<v4f*>(o + HWp));
        __builtin_nontemporal_store(s2, reinterpret_cast<v4f*>(o + 2 * HWp));
        __builtin_nontemporal_store(s3, reinterpret_cast<v4f*>(o + 3 * HWp));
    }
}

extern "C" void kernel_launch(void* const* d_in, const int* in_sizes, int n_in,
                              void* d_out, int out_size, void* d_ws, size_t ws_size,
                              hipStream_t stream) {
    const float* feat   = (const float*)d_in[0];
    const int*   coords = (const int*)d_in[1];
    float*       out    = (float*)d_out;

    const int P = in_sizes[0] / CC;        // 96000
    const int B = out_size / (CC * HWp);   // 8

    const size_t winner_bytes = (size_t)B * HWp * sizeof(int);

    if (ws_size >= winner_bytes) {
        // --- primary: winner array in workspace ---
        int* winner = (int*)d_ws;
        hipMemsetAsync(winner, 0, winner_bytes, stream);
        k_winner<<<(P + 255) / 256, 256, 0, stream>>>(coords, winner, HWp, P);
        const int blocksPerBatch = HWp / CELLS2;      // 214272/256 = 837
        const int nblocks = B * blocksPerBatch;       // 6696
        k_gather_lds2<<<nblocks, 256, 0, stream>>>(feat, winner, out, blocksPerBatch);
    } else {
        // --- fallback: winner in out's c=0 plane, thread-per-cell gather ---
        for (int b = 0; b < B; ++b)
            hipMemsetAsync(out + (size_t)b * CC * HWp, 0,
                           (size_t)HWp * sizeof(int), stream);
        k_winner<<<(P + 255) / 256, 256, 0, stream>>>(
            coords, (int*)out, CC * HWp, P);
        const int total = B * HH * W4;
        k_gather_cells<<<(total + 255) / 256, 256, 0, stream>>>(
            feat, (int*)out, CC * HWp, out, total);
    }
}

// Round 8
// 95.615 us; speedup vs baseline: 1.2050x; 1.2050x over previous
//
#include <hip/hip_runtime.h>

// PointPillarsScatter: canvas[b, :, y, x] = feat[p, :], last-writer-wins.
// Phase 1: memset winner; Phase 2: winner[b,y,x] = max(p)+1 via atomicMax;
// Phase 3: LDS-transpose gather, R6 geometry (128 cells/block, 33KB LDS,
// 4 blocks/CU) but CHANNEL-MAJOR LDS tr[64][129]:
//   load:  16 lanes per pillar row -> 256B coalesced feat reads; 4 scalar
//          ds_writes at bank (4*ln+j+row) mod 32 -> 2 lanes/bank = free.
//   store: wave-half per channel: ONE contiguous conflict-free ds_read_b128
//          + 512B nontemporal store run per channel per round.
// vs R6: kills the 8-way store-phase LDS read conflict; occupancy unchanged.

constexpr int HH  = 496;
constexpr int WW  = 432;
constexpr int CC  = 64;
constexpr int HWp = HH * WW;    // 214272
constexpr int W4  = WW / 4;     // 108
constexpr int CELLS = 128;      // cells per block
constexpr int PAD   = 129;      // LDS channel-row stride in floats (odd)

typedef float v4f __attribute__((ext_vector_type(4)));

// Zero-initialized device global: the "feature row" of empty cells (fallback).
__device__ float g_zero_row[CC];

__global__ void k_winner(const int* __restrict__ coords, int* __restrict__ winner,
                         int wstride, int P) {
    int p = blockIdx.x * blockDim.x + threadIdx.x;
    if (p >= P) return;
    int4 c4 = reinterpret_cast<const int4*>(coords)[p];  // (b, z, y, x)
    atomicMax(&winner[c4.x * wstride + c4.z * WW + c4.w], p + 1);
}

__global__ __launch_bounds__(256) void k_gather_cm(
        const float* __restrict__ feat, const int* __restrict__ winner,
        float* __restrict__ out, int blocksPerBatch) {
    __shared__ float tr[CC * PAD];   // 64 x 129 x 4B = 33,024 B -> 4 blocks/CU

    const int bb       = blockIdx.x / blocksPerBatch;
    const int cellbase = (blockIdx.x % blocksPerBatch) * CELLS;
    const int t   = threadIdx.x;
    const int grp = t >> 4;   // 0..15 (row group in load phase)
    const int ln  = t & 15;   // 0..15 (channel-quad lane)

    const int* wbase = winner + bb * HWp + cellbase;

    // --- load phase: 8 rounds x 16 rows; write channel-major (transposed) ---
    #pragma unroll
    for (int r = 0; r < 8; ++r) {
        int row = r * 16 + grp;
        int w = wbase[row];                       // broadcast within 16-lane group
        v4f v = {0.0f, 0.0f, 0.0f, 0.0f};
        if (w > 0)
            v = *reinterpret_cast<const v4f*>(feat + (size_t)(w - 1) * CC + ln * 4);
        tr[(ln * 4 + 0) * PAD + row] = v.x;
        tr[(ln * 4 + 1) * PAD + row] = v.y;
        tr[(ln * 4 + 2) * PAD + row] = v.z;
        tr[(ln * 4 + 3) * PAD + row] = v.w;
    }
    __syncthreads();

    // --- store phase: 8 rounds x 8 channel-groups; contiguous b128 reads,
    //     512B contiguous nontemporal store run per channel ---
    const int qv = t & 31;    // v4f index within the channel's 512B span
    const int cg = t >> 5;    // 0..7
    float* obase = out + (size_t)bb * CC * HWp + cellbase;
    #pragma unroll
    for (int r = 0; r < 8; ++r) {
        int c = r * 8 + cg;
        v4f s = *reinterpret_cast<const v4f*>(&tr[c * PAD + qv * 4]);
        __builtin_nontemporal_store(
            s, reinterpret_cast<v4f*>(obase + (size_t)c * HWp + qv * 4));
    }
}

// ---- fallback gather (ws too small): winner lives in out's c=0 plane.
// Thread-per-cell, reads its own winner quad exactly once before overwriting.
__global__ __launch_bounds__(256) void k_gather_cells(
        const float* __restrict__ feat, const int* __restrict__ winner,
        int wstride, float* __restrict__ out, int total) {
    int t = blockIdx.x * blockDim.x + threadIdx.x;
    if (t >= total) return;
    int x4 = t % W4;  int r = t / W4;
    int y  = r % HH;  int bb = r / HH;
    const int4 win = *reinterpret_cast<const int4*>(
        &winner[bb * wstride + y * WW + x4 * 4]);
    const float* f0 = (win.x > 0) ? feat + (size_t)(win.x - 1) * CC : g_zero_row;
    const float* f1 = (win.y > 0) ? feat + (size_t)(win.y - 1) * CC : g_zero_row;
    const float* f2 = (win.z > 0) ? feat + (size_t)(win.z - 1) * CC : g_zero_row;
    const float* f3 = (win.w > 0) ? feat + (size_t)(win.w - 1) * CC : g_zero_row;
    float* ob = out + ((size_t)bb * CC * HH + y) * WW + x4 * 4;
    #pragma unroll 4
    for (int cq = 0; cq < CC / 4; ++cq) {
        v4f a = *reinterpret_cast<const v4f*>(f0 + cq * 4);
        v4f b = *reinterpret_cast<const v4f*>(f1 + cq * 4);
        v4f c = *reinterpret_cast<const v4f*>(f2 + cq * 4);
        v4f d = *reinterpret_cast<const v4f*>(f3 + cq * 4);
        float* o = ob + (size_t)cq * 4 * HWp;
        v4f s0 = {a.x, b.x, c.x, d.x};
        v4f s1 = {a.y, b.y, c.y, d.y};
        v4f s2 = {a.z, b.z, c.z, d.z};
        v4f s3 = {a.w, b.w, c.w, d.w};
        __builtin_nontemporal_store(s0, reinterpret_cast<v4f*>(o));
        __builtin_nontemporal_store(s1, reinterpret_cast<v4f*>(o + HWp));
        __builtin_nontemporal_store(s2, reinterpret_cast<v4f*>(o + 2 * HWp));
        __builtin_nontemporal_store(s3, reinterpret_cast<v4f*>(o + 3 * HWp));
    }
}

extern "C" void kernel_launch(void* const* d_in, const int* in_sizes, int n_in,
                              void* d_out, int out_size, void* d_ws, size_t ws_size,
                              hipStream_t stream) {
    const float* feat   = (const float*)d_in[0];
    const int*   coords = (const int*)d_in[1];
    float*       out    = (float*)d_out;

    const int P = in_sizes[0] / CC;        // 96000
    const int B = out_size / (CC * HWp);   // 8

    const size_t winner_bytes = (size_t)B * HWp * sizeof(int);

    if (ws_size >= winner_bytes) {
        // --- primary: winner array in workspace ---
        int* winner = (int*)d_ws;
        hipMemsetAsync(winner, 0, winner_bytes, stream);
        k_winner<<<(P + 255) / 256, 256, 0, stream>>>(coords, winner, HWp, P);
        const int blocksPerBatch = HWp / CELLS;       // 214272/128 = 1674
        const int nblocks = B * blocksPerBatch;       // 13392
        k_gather_cm<<<nblocks, 256, 0, stream>>>(feat, winner, out, blocksPerBatch);
    } else {
        // --- fallback: winner in out's c=0 plane, thread-per-cell gather ---
        for (int b = 0; b < B; ++b)
            hipMemsetAsync(out + (size_t)b * CC * HWp, 0,
                           (size_t)HWp * sizeof(int), stream);
        k_winner<<<(P + 255) / 256, 256, 0, stream>>>(
            coords, (int*)out, CC * HWp, P);
        const int total = B * HH * W4;
        k_gather_cells<<<(total + 255) / 256, 256, 0, stream>>>(
            feat, (int*)out, CC * HWp, out, total);
    }
}